// Round 10
// baseline (1928.825 us; speedup 1.0000x reference)
//
#include <hip/hip_runtime.h>
#include <hip/hip_bf16.h>
#include <math.h>

#define T_STEPS 512
#define BATCH   1024

typedef __attribute__((ext_vector_type(8))) short short8;
typedef __attribute__((ext_vector_type(4))) float f32x4;

#define MFMA16(A, B, C) __builtin_amdgcn_mfma_f32_16x16x32_bf16((A), (B), (C), 0, 0, 0)

// LDS-only barrier (round-9-verified safe; keeps global archive traffic off
// the serial path even though that wasn't the dominant cost).
__device__ __forceinline__ void lds_barrier() {
    asm volatile("s_waitcnt lgkmcnt(0)" ::: "memory");
    __builtin_amdgcn_s_barrier();
}

__device__ __forceinline__ float fast_sigm(float z) {
    return __fdividef(1.0f, 1.0f + __expf(-z));
}
__device__ __forceinline__ float fast_tanh(float z) {
    return fmaf(2.0f, __fdividef(1.0f, 1.0f + __expf(-2.0f * z)), -1.0f);
}
__device__ __forceinline__ unsigned short f2bf(float f) {
    unsigned int u = __float_as_uint(f);
    u += 0x7fffu + ((u >> 16) & 1u);
    return (unsigned short)(u >> 16);
}
// linear k-slot gather (A/B pair must both be LIN)
__device__ __forceinline__ short8 ldfrag_lin(const float* __restrict__ p) {
    short8 r;
#pragma unroll
    for (int e = 0; e < 8; ++e) r[e] = (short)f2bf(p[e]);
    return r;
}
// sigma2 gather: k-slot (lg,e) <-> col (e>>2)*16 + lg*4 + (e&3)
__device__ __forceinline__ short8 ldfrag_s2(const float* __restrict__ p, int lg) {
    short8 r;
#pragma unroll
    for (int e = 0; e < 8; ++e) r[e] = (short)f2bf(p[(e >> 2) * 16 + lg * 4 + (e & 3)]);
    return r;
}

// ===========================================================================
// K1: layer-1 fwd AND rev chains INTERLEAVED in the same waves. 64 blocks
// (one per 16-batch tile) x 256 thr. Per step each wave does its 16-unit
// slice for both directions (16 MFMA + 2x activations); the two chains are
// dependence-free, so one chain's issue fills the other's stalls. One
// barrier per step. Archives both directions (layout = round-8).
// ===========================================================================
__global__ __launch_bounds__(256, 1) void l1pair_kernel(
    const float* __restrict__ x,
    const float* __restrict__ whh1f, const float* __restrict__ wih1f, const float* __restrict__ b1f,
    const float* __restrict__ whh1r, const float* __restrict__ wih1r, const float* __restrict__ b1r,
    unsigned short* __restrict__ arch_f, unsigned short* __restrict__ arch_r)
{
    __shared__ __align__(16) float xT[T_STEPS][20];
    __shared__ __align__(16) short hF[2][16][72];
    __shared__ __align__(16) short hR[2][16][72];

    const int tile = blockIdx.x, tid = threadIdx.x;
    const int wv = tid >> 6, l = tid & 63, lg = l >> 4, lr = l & 15;

    for (int i = tid; i < T_STEPS * 16; i += 256) {
        const int b = i >> 9, t = i & 511;
        xT[t][b] = x[(size_t)(tile * 16 + b) * T_STEPS + t];
    }
    for (int i = tid; i < 2 * 16 * 72; i += 256) { ((short*)hF)[i] = 0; ((short*)hR)[i] = 0; }

    short8 BF[8], BR_[8];
    float wf[4], bfv[4], wr[4], brv[4];
#pragma unroll
    for (int g = 0; g < 4; ++g) {
        const int row = g * 64 + wv * 16 + lr;
        BF[2 * g]      = ldfrag_lin(whh1f + row * 64 + lg * 8);
        BF[2 * g + 1]  = ldfrag_lin(whh1f + row * 64 + 32 + lg * 8);
        BR_[2 * g]     = ldfrag_lin(whh1r + row * 64 + lg * 8);
        BR_[2 * g + 1] = ldfrag_lin(whh1r + row * 64 + 32 + lg * 8);
        wf[g] = wih1f[row]; bfv[g] = b1f[row];
        wr[g] = wih1r[row]; brv[g] = b1r[row];
    }
    float cF[4] = {0.f, 0.f, 0.f, 0.f};
    float cR[4] = {0.f, 0.f, 0.f, 0.f};
    unsigned short* __restrict__ abF = arch_f + (size_t)tile * T_STEPS * 16 * 64;
    unsigned short* __restrict__ abR = arch_r + (size_t)tile * T_STEPS * 16 * 64;
    __syncthreads();

    for (int i = 0; i < T_STEPS; ++i) {
        const int tF = i, tR = T_STEPS - 1 - i;
        const short8 fa0 = *(const short8*)&hF[(tF + 1) & 1][lr][lg * 8];
        const short8 fa1 = *(const short8*)&hF[(tF + 1) & 1][lr][32 + lg * 8];
        const short8 ra0 = *(const short8*)&hR[(tR + 1) & 1][lr][lg * 8];
        const short8 ra1 = *(const short8*)&hR[(tR + 1) & 1][lr][32 + lg * 8];
        f32x4 zF[4], zR[4];
#pragma unroll
        for (int g = 0; g < 4; ++g) {
            f32x4 a = {0.f, 0.f, 0.f, 0.f}, b = {0.f, 0.f, 0.f, 0.f};
            a = MFMA16(fa0, BF[2 * g], a);
            b = MFMA16(fa1, BF[2 * g + 1], b);
            zF[g] = a + b;
            f32x4 c = {0.f, 0.f, 0.f, 0.f}, d = {0.f, 0.f, 0.f, 0.f};
            c = MFMA16(ra0, BR_[2 * g], c);
            d = MFMA16(ra1, BR_[2 * g + 1], d);
            zR[g] = c + d;
        }
        const float4 xf = *(const float4*)&xT[tF][lg * 4];
        const float4 xr = *(const float4*)&xT[tR][lg * 4];
        const float xaF[4] = {xf.x, xf.y, xf.z, xf.w};
        const float xaR[4] = {xr.x, xr.y, xr.z, xr.w};
#pragma unroll
        for (int j = 0; j < 4; ++j) {
            {   // forward chain
                const float vi = fast_sigm(zF[0][j] + fmaf(xaF[j], wf[0], bfv[0]));
                const float vg_f = fast_sigm(zF[1][j] + fmaf(xaF[j], wf[1], bfv[1]));
                const float vg = fast_tanh(zF[2][j] + fmaf(xaF[j], wf[2], bfv[2]));
                const float vo = fast_sigm(zF[3][j] + fmaf(xaF[j], wf[3], bfv[3]));
                cF[j] = fmaf(vg_f, cF[j], vi * vg);
                const float h = vo * fast_tanh(cF[j]);
                const unsigned short hb = f2bf(h);
                hF[tF & 1][lg * 4 + j][wv * 16 + lr] = (short)hb;
                abF[((size_t)tF * 16 + lg * 4 + j) * 64 + wv * 16 + lr] = hb;
            }
            {   // reverse chain (independent -> fills fwd's stalls)
                const float vi = fast_sigm(zR[0][j] + fmaf(xaR[j], wr[0], brv[0]));
                const float vg_f = fast_sigm(zR[1][j] + fmaf(xaR[j], wr[1], brv[1]));
                const float vg = fast_tanh(zR[2][j] + fmaf(xaR[j], wr[2], brv[2]));
                const float vo = fast_sigm(zR[3][j] + fmaf(xaR[j], wr[3], brv[3]));
                cR[j] = fmaf(vg_f, cR[j], vi * vg);
                const float h = vo * fast_tanh(cR[j]);
                const unsigned short hb = f2bf(h);
                hR[tR & 1][lg * 4 + j][wv * 16 + lr] = (short)hb;
                abR[((size_t)tR * 16 + lg * 4 + j) * 64 + wv * 16 + lr] = hb;
            }
        }
        lds_barrier();
    }
}

// ---------------------------------------------------------------------------
// L2 epilogue (round-8 verified): rev single step @ T-1 (zero state) + head.
// ---------------------------------------------------------------------------
__device__ __forceinline__ void l2_tail(
    int lg, int lr, int l,
    const unsigned short* __restrict__ af, const unsigned short* __restrict__ ar,
    const short* __restrict__ h2last,   // &h2X[1][0][0], row stride 40 shorts
    const float* __restrict__ wih2r, const float* __restrict__ b2r,
    const float* __restrict__ w_fc1, const float* __restrict__ b_fc1,
    const float* __restrict__ w_out, const float* __restrict__ b_out,
    float* __restrict__ outp)
{
    short8 Bb = {0, 0, 0, 0, 0, 0, 0, 0};
    if (lg == 0) Bb[0] = (short)0x3F80;                   // B = [1, 0, ...]
    const short8 f0 = *(const short8*)(af + (size_t)((T_STEPS - 1) * 16 + lr) * 64 + lg * 8);
    const short8 f1 = *(const short8*)(af + (size_t)((T_STEPS - 1) * 16 + lr) * 64 + 32 + lg * 8);
    const short8 r0 = *(const short8*)(ar + (size_t)((T_STEPS - 1) * 16 + lr) * 64 + lg * 8);
    const short8 r1 = *(const short8*)(ar + (size_t)((T_STEPS - 1) * 16 + lr) * 64 + 32 + lg * 8);
    f32x4 ze[8];
#pragma unroll
    for (int mm = 0; mm < 8; ++mm) {
        const int row = mm * 16 + lr;                     // gate-major LIN rows
        const short8 A0 = ldfrag_lin(wih2r + row * 128 + lg * 8);
        const short8 A1 = ldfrag_lin(wih2r + row * 128 + 32 + lg * 8);
        const short8 A2 = ldfrag_lin(wih2r + row * 128 + 64 + lg * 8);
        const short8 A3 = ldfrag_lin(wih2r + row * 128 + 96 + lg * 8);
        short8 bf = {0, 0, 0, 0, 0, 0, 0, 0};
        if (lg == 0) bf[0] = (short)f2bf(b2r[row]);
        f32x4 za = {0.f, 0.f, 0.f, 0.f}, zb = {0.f, 0.f, 0.f, 0.f};
        za = MFMA16(A0, f0, za);
        za = MFMA16(A2, r0, za);
        za = MFMA16(bf, Bb, za);
        zb = MFMA16(A1, f1, zb);
        zb = MFMA16(A3, r1, zb);
        ze[mm] = za + zb;
    }
    short8 BR = {0, 0, 0, 0, 0, 0, 0, 0};   // h2r(511), lane-natural sigma2
#pragma unroll
    for (int uh = 0; uh < 2; ++uh) {
#pragma unroll
        for (int j = 0; j < 4; ++j) {
            const float vi = fast_sigm(ze[uh][j]);        // c0=0: f-gate irrelevant
            const float vg = fast_tanh(ze[4 + uh][j]);
            const float vo = fast_sigm(ze[6 + uh][j]);
            BR[uh * 4 + j] = (short)f2bf(vo * fast_tanh(vi * vg));
        }
    }
    const short8 Bx = *(const short8*)(h2last + lr * 40 + lg * 8);  // h2f(511), LIN
    float part = 0.f;
#pragma unroll
    for (int mm = 0; mm < 4; ++mm) {
        const int row = mm * 16 + lr;
        const short8 A0 = ldfrag_lin(w_fc1 + row * 64 + lg * 8);   // cols 0-31 LIN
        const short8 A1 = ldfrag_s2(w_fc1 + row * 64 + 32, lg);    // cols 32-63 s2
        short8 bf = {0, 0, 0, 0, 0, 0, 0, 0};
        if (lg == 0) bf[0] = (short)f2bf(b_fc1[row]);
        f32x4 a = {0.f, 0.f, 0.f, 0.f};
        a = MFMA16(A0, Bx, a);
        a = MFMA16(A1, BR, a);
        a = MFMA16(bf, Bb, a);
#pragma unroll
        for (int j = 0; j < 4; ++j)
            part += fmaxf(a[j], 0.f) * w_out[mm * 16 + lg * 4 + j];
    }
    part += __shfl_xor(part, 16, 64);
    part += __shfl_xor(part, 32, 64);
    if (l < 16) outp[lr] = fast_sigm(part + b_out[0]);
}

// ===========================================================================
// K2: layer-2 forward for TWO batch-tiles interleaved per block. 32 blocks
// x 512 thr (8 waves). Per wave per step: 2 x (1 critical MFMA + 4 off-path
// zpre MFMA + lane-local gates). Gate-interleaved rows (round-8 verified):
// orig(r) = (r&3)*32 + 4*wv + (r>>2). Weights shared across tiles. One
// barrier/step. Epilogues on wave0 (tile A) and wave4 (tile B).
// ===========================================================================
__global__ __launch_bounds__(512, 1) void l2pair_kernel(
    const float* __restrict__ wih2f, const float* __restrict__ whh2f, const float* __restrict__ b2f,
    const float* __restrict__ wih2r, const float* __restrict__ b2r,
    const float* __restrict__ w_fc1, const float* __restrict__ b_fc1,
    const float* __restrict__ w_out, const float* __restrict__ b_out,
    const unsigned short* __restrict__ arch_f, const unsigned short* __restrict__ arch_r,
    float* __restrict__ out)
{
    __shared__ __align__(16) short h2A[2][16][40];
    __shared__ __align__(16) short h2B[2][16][40];

    const int blk = blockIdx.x, tid = threadIdx.x;
    const int wv = tid >> 6, l = tid & 63, lg = l >> 4, lr = l & 15;
    const int tA = 2 * blk, tB = 2 * blk + 1;
    const unsigned short* __restrict__ afA = arch_f + (size_t)tA * T_STEPS * 16 * 64;
    const unsigned short* __restrict__ arA = arch_r + (size_t)tA * T_STEPS * 16 * 64;
    const unsigned short* __restrict__ afB = arch_f + (size_t)tB * T_STEPS * 16 * 64;
    const unsigned short* __restrict__ arB = arch_r + (size_t)tB * T_STEPS * 16 * 64;

    const int orow = (lr & 3) * 32 + 4 * wv + (lr >> 2);   // interleaved row map
    short8 AF[5];
    AF[0] = ldfrag_lin(wih2f + orow * 128 + lg * 8);        // hf k 0-31
    AF[1] = ldfrag_lin(wih2f + orow * 128 + 32 + lg * 8);   // hf k 32-63
    AF[2] = ldfrag_lin(wih2f + orow * 128 + 64 + lg * 8);   // hr k 0-31
    AF[3] = ldfrag_lin(wih2f + orow * 128 + 96 + lg * 8);   // hr k 32-63
    AF[4] = ldfrag_lin(whh2f + orow * 32 + lg * 8);         // h2 k 0-31
    float b2v[4];
#pragma unroll
    for (int j = 0; j < 4; ++j) b2v[j] = b2f[j * 32 + 4 * wv + lg];

    for (int i = tid; i < 2 * 16 * 40; i += 512) { ((short*)h2A)[i] = 0; ((short*)h2B)[i] = 0; }

    // prologue: zcur = zpre(0) for both tiles; prefetch step-1 frags
    short8 pfA0 = *(const short8*)(afA + (size_t)lr * 64 + lg * 8);
    short8 pfA1 = *(const short8*)(afA + (size_t)lr * 64 + 32 + lg * 8);
    short8 prA0 = *(const short8*)(arA + (size_t)lr * 64 + lg * 8);
    short8 prA1 = *(const short8*)(arA + (size_t)lr * 64 + 32 + lg * 8);
    short8 pfB0 = *(const short8*)(afB + (size_t)lr * 64 + lg * 8);
    short8 pfB1 = *(const short8*)(afB + (size_t)lr * 64 + 32 + lg * 8);
    short8 prB0 = *(const short8*)(arB + (size_t)lr * 64 + lg * 8);
    short8 prB1 = *(const short8*)(arB + (size_t)lr * 64 + 32 + lg * 8);
    f32x4 zcurA = {0.f, 0.f, 0.f, 0.f}, zcurB = {0.f, 0.f, 0.f, 0.f};
    zcurA = MFMA16(AF[0], pfA0, zcurA);
    zcurA = MFMA16(AF[1], pfA1, zcurA);
    zcurA = MFMA16(AF[2], prA0, zcurA);
    zcurA = MFMA16(AF[3], prA1, zcurA);
    zcurB = MFMA16(AF[0], pfB0, zcurB);
    zcurB = MFMA16(AF[1], pfB1, zcurB);
    zcurB = MFMA16(AF[2], prB0, zcurB);
    zcurB = MFMA16(AF[3], prB1, zcurB);
    pfA0 = *(const short8*)(afA + (size_t)(16 + lr) * 64 + lg * 8);
    pfA1 = *(const short8*)(afA + (size_t)(16 + lr) * 64 + 32 + lg * 8);
    prA0 = *(const short8*)(arA + (size_t)(16 + lr) * 64 + lg * 8);
    prA1 = *(const short8*)(arA + (size_t)(16 + lr) * 64 + 32 + lg * 8);
    pfB0 = *(const short8*)(afB + (size_t)(16 + lr) * 64 + lg * 8);
    pfB1 = *(const short8*)(afB + (size_t)(16 + lr) * 64 + 32 + lg * 8);
    prB0 = *(const short8*)(arB + (size_t)(16 + lr) * 64 + lg * 8);
    prB1 = *(const short8*)(arB + (size_t)(16 + lr) * 64 + 32 + lg * 8);

    float c2A = 0.f, c2B = 0.f;
    __syncthreads();

    for (int s = 0; s < T_STEPS; ++s) {
        // critical MFMAs (independent across tiles)
        const short8 bhA = *(const short8*)&h2A[(s + 1) & 1][lr][lg * 8];
        const short8 bhB = *(const short8*)&h2B[(s + 1) & 1][lr][lg * 8];
        const f32x4 zA = MFMA16(AF[4], bhA, zcurA);
        const f32x4 zB = MFMA16(AF[4], bhB, zcurB);
        // off-path: zpre(s+1); prefetch (s+2)
        f32x4 znA = {0.f, 0.f, 0.f, 0.f}, znB = {0.f, 0.f, 0.f, 0.f};
        znA = MFMA16(AF[0], pfA0, znA);
        znA = MFMA16(AF[1], pfA1, znA);
        znA = MFMA16(AF[2], prA0, znA);
        znA = MFMA16(AF[3], prA1, znA);
        znB = MFMA16(AF[0], pfB0, znB);
        znB = MFMA16(AF[1], pfB1, znB);
        znB = MFMA16(AF[2], prB0, znB);
        znB = MFMA16(AF[3], prB1, znB);
        if (s + 2 < T_STEPS) {
            const size_t o = (size_t)((s + 2) * 16 + lr) * 64 + lg * 8;
            pfA0 = *(const short8*)(afA + o);
            pfA1 = *(const short8*)(afA + o + 32);
            prA0 = *(const short8*)(arA + o);
            prA1 = *(const short8*)(arA + o + 32);
            pfB0 = *(const short8*)(afB + o);
            pfB1 = *(const short8*)(afB + o + 32);
            prB0 = *(const short8*)(arB + o);
            prB1 = *(const short8*)(arB + o + 32);
        }
        // lane-local gates, tile A
        {
            const float vi = fast_sigm(zA[0] + b2v[0]);
            const float vf = fast_sigm(zA[1] + b2v[1]);
            const float vg = fast_tanh(zA[2] + b2v[2]);
            const float vo = fast_sigm(zA[3] + b2v[3]);
            c2A = fmaf(vf, c2A, vi * vg);
            h2A[s & 1][lr][4 * wv + lg] = (short)f2bf(vo * fast_tanh(c2A));
        }
        // lane-local gates, tile B (independent -> fills A's stalls)
        {
            const float vi = fast_sigm(zB[0] + b2v[0]);
            const float vf = fast_sigm(zB[1] + b2v[1]);
            const float vg = fast_tanh(zB[2] + b2v[2]);
            const float vo = fast_sigm(zB[3] + b2v[3]);
            c2B = fmaf(vf, c2B, vi * vg);
            h2B[s & 1][lr][4 * wv + lg] = (short)f2bf(vo * fast_tanh(c2B));
        }
        zcurA = znA; zcurB = znB;
        lds_barrier();
    }

    if (wv == 0)
        l2_tail(lg, lr, l, afA, arA, &h2A[1][0][0],
                wih2r, b2r, w_fc1, b_fc1, w_out, b_out, out + tA * 16);
    else if (wv == 4)
        l2_tail(lg, lr, l, afB, arB, &h2B[1][0][0],
                wih2r, b2r, w_fc1, b_fc1, w_out, b_out, out + tB * 16);
}

// ---------------------------------------------------------------------------
extern "C" void kernel_launch(void* const* d_in, const int* in_sizes, int n_in,
                              void* d_out, int out_size, void* d_ws, size_t ws_size,
                              hipStream_t stream) {
    const float* x     = (const float*)d_in[0];
    const float* wih1f = (const float*)d_in[1];
    const float* whh1f = (const float*)d_in[2];
    const float* b1f   = (const float*)d_in[3];
    const float* wih1r = (const float*)d_in[4];
    const float* whh1r = (const float*)d_in[5];
    const float* b1r   = (const float*)d_in[6];
    const float* wih2f = (const float*)d_in[7];
    const float* whh2f = (const float*)d_in[8];
    const float* b2f   = (const float*)d_in[9];
    const float* wih2r = (const float*)d_in[10];
    // d_in[11] = whh2r unused: layer-2 reverse runs exactly one step from zero state
    const float* b2r   = (const float*)d_in[12];
    const float* w_fc1 = (const float*)d_in[13];
    const float* b_fc1 = (const float*)d_in[14];
    const float* w_out = (const float*)d_in[15];
    const float* b_out = (const float*)d_in[16];
    float* out = (float*)d_out;

    // ws >= 128 MB proven: rounds 8-9 executed the 128 MB dual-archive path.
    unsigned short* arch_f = (unsigned short*)d_ws;
    unsigned short* arch_r = arch_f + (size_t)64 * T_STEPS * 16 * 64;

    l1pair_kernel<<<dim3(64), dim3(256), 0, stream>>>(
        x, whh1f, wih1f, b1f, whh1r, wih1r, b1r, arch_f, arch_r);
    l2pair_kernel<<<dim3(32), dim3(512), 0, stream>>>(
        wih2f, whh2f, b2f, wih2r, b2r,
        w_fc1, b_fc1, w_out, b_out, arch_f, arch_r, out);
}

// Round 11
// 792.563 us; speedup vs baseline: 2.4337x; 2.4337x over previous
//
#include <hip/hip_runtime.h>
#include <hip/hip_bf16.h>
#include <math.h>

#define T_STEPS 512
#define BATCH   1024
#define NL2E    (-1.44269504f)   // -log2(e)

typedef __attribute__((ext_vector_type(8))) short short8;
typedef __attribute__((ext_vector_type(4))) float f32x4;

#define MFMA16(A, B, C) __builtin_amdgcn_mfma_f32_16x16x32_bf16((A), (B), (C), 0, 0, 0)

// LDS-only barrier (round-9-verified safe).
__device__ __forceinline__ void lds_barrier() {
    asm volatile("s_waitcnt lgkmcnt(0)" ::: "memory");
    __builtin_amdgcn_s_barrier();
}

// Raw-hardware activations. Inputs are PRESCALED: zs = -log2e*z (sigmoid),
// zs = -2log2e*z (tanh). sigma(z) = rcp(1+2^zs); tanh(z) = 2*rcp(1+2^zs)-1.
// (__fdividef in HIP headers is plain x/y -> IEEE div sequence ~12 instrs;
// that was ~half the per-step VALU issue. rcp+exp2 = 2 instrs.)
__device__ __forceinline__ float psig(float zs) {
    return __builtin_amdgcn_rcpf(1.0f + __builtin_amdgcn_exp2f(zs));
}
__device__ __forceinline__ float ptanh(float zs) {
    return fmaf(2.0f, __builtin_amdgcn_rcpf(1.0f + __builtin_amdgcn_exp2f(zs)), -1.0f);
}
__device__ __forceinline__ float tanh_c(float c) {   // unprescaled input
    return fmaf(2.0f, __builtin_amdgcn_rcpf(
        1.0f + __builtin_amdgcn_exp2f(2.0f * NL2E * c)), -1.0f);
}
__device__ __forceinline__ unsigned short f2bf(float f) {
    unsigned int u = __float_as_uint(f);
    u += 0x7fffu + ((u >> 16) & 1u);
    return (unsigned short)(u >> 16);
}
// linear k-slot gather with scale folded in before bf16 rounding
__device__ __forceinline__ short8 ldfrag_lin_s(const float* __restrict__ p, float s) {
    short8 r;
#pragma unroll
    for (int e = 0; e < 8; ++e) r[e] = (short)f2bf(p[e] * s);
    return r;
}
__device__ __forceinline__ short8 ldfrag_lin(const float* __restrict__ p) {
    return ldfrag_lin_s(p, 1.0f);
}
// sigma2 gather: k-slot (lg,e) <-> col (e>>2)*16 + lg*4 + (e&3)
__device__ __forceinline__ short8 ldfrag_s2(const float* __restrict__ p, int lg) {
    short8 r;
#pragma unroll
    for (int e = 0; e < 8; ++e) r[e] = (short)f2bf(p[(e >> 2) * 16 + lg * 4 + (e & 3)]);
    return r;
}

// ===========================================================================
// K1-dual: layer-1 BOTH directions concurrently. 128 blocks x 256 thr.
// Even blocks: forward -> arch_f; odd: reverse -> arch_r. Weights prescaled
// by -log2e (gates i,f,o) / -2log2e (gate g) at fragment load.
// ===========================================================================
__global__ __launch_bounds__(256, 1) void l1dual_kernel(
    const float* __restrict__ x,
    const float* __restrict__ whh1f, const float* __restrict__ wih1f, const float* __restrict__ b1f,
    const float* __restrict__ whh1r, const float* __restrict__ wih1r, const float* __restrict__ b1r,
    unsigned short* __restrict__ arch_f, unsigned short* __restrict__ arch_r)
{
    __shared__ __align__(16) float xT[T_STEPS][20];
    __shared__ __align__(16) short hT[2][16][72];

    const int blk = blockIdx.x;
    const int dir = blk & 1;            // 0 = fwd, 1 = rev
    const int tile = blk >> 1;
    const int tid = threadIdx.x;
    const int wv = tid >> 6, l = tid & 63, lg = l >> 4, lr = l & 15;

    const float* __restrict__ whh = dir ? whh1r : whh1f;
    const float* __restrict__ wih = dir ? wih1r : wih1f;
    const float* __restrict__ bbp = dir ? b1r : b1f;
    unsigned short* __restrict__ archb =
        (dir ? arch_r : arch_f) + (size_t)tile * T_STEPS * 16 * 64;

    for (int i = tid; i < T_STEPS * 16; i += 256) {
        const int b = i >> 9, t = i & 511;
        xT[t][b] = x[(size_t)(tile * 16 + b) * T_STEPS + t];
    }
    for (int i = tid; i < 2 * 16 * 72; i += 256) ((short*)hT)[i] = 0;

    short8 BW[8]; float wihv[4], bvv[4];
#pragma unroll
    for (int g = 0; g < 4; ++g) {
        const float sf = (g == 2) ? 2.0f * NL2E : NL2E;
        const int row = g * 64 + wv * 16 + lr;
        BW[2 * g]     = ldfrag_lin_s(whh + row * 64 + lg * 8, sf);
        BW[2 * g + 1] = ldfrag_lin_s(whh + row * 64 + 32 + lg * 8, sf);
        wihv[g] = wih[row] * sf; bvv[g] = bbp[row] * sf;
    }
    float cst[4] = {0.f, 0.f, 0.f, 0.f};
    __syncthreads();

    for (int i = 0; i < T_STEPS; ++i) {
        const int t = dir ? (T_STEPS - 1 - i) : i;
        const int rp = (t + 1) & 1;     // parity of previous step (both dirs)
        const short8 a0 = *(const short8*)&hT[rp][lr][lg * 8];
        const short8 a1 = *(const short8*)&hT[rp][lr][32 + lg * 8];
        f32x4 z[4];
#pragma unroll
        for (int g = 0; g < 4; ++g) {
            f32x4 za = {0.f, 0.f, 0.f, 0.f}, zb = {0.f, 0.f, 0.f, 0.f};
            za = MFMA16(a0, BW[2 * g], za);
            zb = MFMA16(a1, BW[2 * g + 1], zb);
            z[g] = za + zb;
        }
        const float4 x4v = *(const float4*)&xT[t][lg * 4];
        const float xa[4] = {x4v.x, x4v.y, x4v.z, x4v.w};
#pragma unroll
        for (int j = 0; j < 4; ++j) {
            const float vi = psig (z[0][j] + fmaf(xa[j], wihv[0], bvv[0]));
            const float vf = psig (z[1][j] + fmaf(xa[j], wihv[1], bvv[1]));
            const float vg = ptanh(z[2][j] + fmaf(xa[j], wihv[2], bvv[2]));
            const float vo = psig (z[3][j] + fmaf(xa[j], wihv[3], bvv[3]));
            cst[j] = fmaf(vf, cst[j], vi * vg);
            const float h = vo * tanh_c(cst[j]);
            const unsigned short hb = f2bf(h);
            hT[t & 1][lg * 4 + j][wv * 16 + lr] = (short)hb;
            archb[((size_t)t * 16 + lg * 4 + j) * 64 + wv * 16 + lr] = hb;
        }
        lds_barrier();
    }
}

// ===========================================================================
// K3: layer-2 forward recurrence + rev step + head. 64 blocks x 512 thr.
// Gate-interleaved rows: orig(r) = (r&3)*32 + 4*wv + (r>>2); lane's 4 C
// values are gates i,f,g,o of unit (4*wv+lg), batch lr. All five A-frags
// prescaled per-row by the row's gate factor (gate = lr&3).
// ===========================================================================
__global__ __launch_bounds__(512, 1) void l2top_kernel(
    const float* __restrict__ wih2f, const float* __restrict__ whh2f, const float* __restrict__ b2f,
    const float* __restrict__ wih2r, const float* __restrict__ b2r,
    const float* __restrict__ w_fc1, const float* __restrict__ b_fc1,
    const float* __restrict__ w_out, const float* __restrict__ b_out,
    const unsigned short* __restrict__ arch_f, const unsigned short* __restrict__ arch_r,
    float* __restrict__ out)
{
    __shared__ __align__(16) short h2X[2][16][40];

    const int bt = blockIdx.x, tid = threadIdx.x;
    const int wv = tid >> 6, l = tid & 63, lg = l >> 4, lr = l & 15;
    const unsigned short* __restrict__ af = arch_f + (size_t)bt * T_STEPS * 16 * 64;
    const unsigned short* __restrict__ ar = arch_r + (size_t)bt * T_STEPS * 16 * 64;

    const int orow = (lr & 3) * 32 + 4 * wv + (lr >> 2);   // interleaved row map
    const float sfr = ((lr & 3) == 2) ? 2.0f * NL2E : NL2E;  // this A-row's gate factor
    short8 AF[5];
    AF[0] = ldfrag_lin_s(wih2f + orow * 128 + lg * 8, sfr);        // hf k 0-31
    AF[1] = ldfrag_lin_s(wih2f + orow * 128 + 32 + lg * 8, sfr);   // hf k 32-63
    AF[2] = ldfrag_lin_s(wih2f + orow * 128 + 64 + lg * 8, sfr);   // hr k 0-31
    AF[3] = ldfrag_lin_s(wih2f + orow * 128 + 96 + lg * 8, sfr);   // hr k 32-63
    AF[4] = ldfrag_lin_s(whh2f + orow * 32 + lg * 8, sfr);         // h2 k 0-31
    float b2v[4];
#pragma unroll
    for (int j = 0; j < 4; ++j)
        b2v[j] = b2f[j * 32 + 4 * wv + lg] * ((j == 2) ? 2.0f * NL2E : NL2E);

    for (int i = tid; i < 2 * 16 * 40; i += 512) ((short*)h2X)[i] = 0;

    // prologue: zcur = zpre(0); prefetch frags for step 1
    short8 pf0 = *(const short8*)(af + (size_t)lr * 64 + lg * 8);
    short8 pf1 = *(const short8*)(af + (size_t)lr * 64 + 32 + lg * 8);
    short8 pr0 = *(const short8*)(ar + (size_t)lr * 64 + lg * 8);
    short8 pr1 = *(const short8*)(ar + (size_t)lr * 64 + 32 + lg * 8);
    f32x4 zcur = {0.f, 0.f, 0.f, 0.f};
    zcur = MFMA16(AF[0], pf0, zcur);
    zcur = MFMA16(AF[1], pf1, zcur);
    zcur = MFMA16(AF[2], pr0, zcur);
    zcur = MFMA16(AF[3], pr1, zcur);
    pf0 = *(const short8*)(af + (size_t)(1 * 16 + lr) * 64 + lg * 8);
    pf1 = *(const short8*)(af + (size_t)(1 * 16 + lr) * 64 + 32 + lg * 8);
    pr0 = *(const short8*)(ar + (size_t)(1 * 16 + lr) * 64 + lg * 8);
    pr1 = *(const short8*)(ar + (size_t)(1 * 16 + lr) * 64 + 32 + lg * 8);

    float c2 = 0.f;
    __syncthreads();

    for (int s = 0; s < T_STEPS; ++s) {
        // ---- critical path: Whh2.h2(s-1) + zcur -> gates -> c2 -> h2(s)
        const short8 bh = *(const short8*)&h2X[(s + 1) & 1][lr][lg * 8];
        const f32x4 z = MFMA16(AF[4], bh, zcur);
        // ---- off-path: zpre(s+1) from prefetched frags; prefetch (s+2)
        f32x4 znxt = {0.f, 0.f, 0.f, 0.f};
        znxt = MFMA16(AF[0], pf0, znxt);
        znxt = MFMA16(AF[1], pf1, znxt);
        znxt = MFMA16(AF[2], pr0, znxt);
        znxt = MFMA16(AF[3], pr1, znxt);
        if (s + 2 < T_STEPS) {
            pf0 = *(const short8*)(af + (size_t)((s + 2) * 16 + lr) * 64 + lg * 8);
            pf1 = *(const short8*)(af + (size_t)((s + 2) * 16 + lr) * 64 + 32 + lg * 8);
            pr0 = *(const short8*)(ar + (size_t)((s + 2) * 16 + lr) * 64 + lg * 8);
            pr1 = *(const short8*)(ar + (size_t)((s + 2) * 16 + lr) * 64 + 32 + lg * 8);
        }
        // ---- lane-local gates (j: 0=i 1=f 2=g 3=o of unit 4*wv+lg, batch lr)
        const float vi = psig (z[0] + b2v[0]);
        const float vf = psig (z[1] + b2v[1]);
        const float vg = ptanh(z[2] + b2v[2]);
        const float vo = psig (z[3] + b2v[3]);
        c2 = fmaf(vf, c2, vi * vg);
        h2X[s & 1][lr][4 * wv + lg] = (short)f2bf(vo * tanh_c(c2));
        zcur = znxt;
        lds_barrier();
    }

    // ===== epilogue (wave 0): L2-reverse single step @ T-1 + MLP head ======
    if (wv == 0) {
        short8 Bb = {0, 0, 0, 0, 0, 0, 0, 0};
        if (lg == 0) Bb[0] = (short)0x3F80;                   // B = [1, 0, ...]
        const short8 f0 = *(const short8*)(af + (size_t)((T_STEPS - 1) * 16 + lr) * 64 + lg * 8);
        const short8 f1 = *(const short8*)(af + (size_t)((T_STEPS - 1) * 16 + lr) * 64 + 32 + lg * 8);
        const short8 r0 = *(const short8*)(ar + (size_t)((T_STEPS - 1) * 16 + lr) * 64 + lg * 8);
        const short8 r1 = *(const short8*)(ar + (size_t)((T_STEPS - 1) * 16 + lr) * 64 + 32 + lg * 8);
        f32x4 ze[8];
#pragma unroll
        for (int mm = 0; mm < 8; ++mm) {
            const int row = mm * 16 + lr;                     // gate-major LIN rows
            const float sfe = ((mm >> 1) == 2) ? 2.0f * NL2E : NL2E;
            const short8 A0 = ldfrag_lin_s(wih2r + row * 128 + lg * 8, sfe);
            const short8 A1 = ldfrag_lin_s(wih2r + row * 128 + 32 + lg * 8, sfe);
            const short8 A2 = ldfrag_lin_s(wih2r + row * 128 + 64 + lg * 8, sfe);
            const short8 A3 = ldfrag_lin_s(wih2r + row * 128 + 96 + lg * 8, sfe);
            short8 bf = {0, 0, 0, 0, 0, 0, 0, 0};
            if (lg == 0) bf[0] = (short)f2bf(b2r[row] * sfe);
            f32x4 za = {0.f, 0.f, 0.f, 0.f}, zb = {0.f, 0.f, 0.f, 0.f};
            za = MFMA16(A0, f0, za);
            za = MFMA16(A2, r0, za);
            za = MFMA16(bf, Bb, za);
            zb = MFMA16(A1, f1, zb);
            zb = MFMA16(A3, r1, zb);
            ze[mm] = za + zb;
        }
        short8 BR = {0, 0, 0, 0, 0, 0, 0, 0};   // h2r(511), lane-natural sigma2
#pragma unroll
        for (int uh = 0; uh < 2; ++uh) {
#pragma unroll
            for (int j = 0; j < 4; ++j) {
                const float vi = psig (ze[uh][j]);            // c0=0: f-gate irrelevant
                const float vg = ptanh(ze[4 + uh][j]);
                const float vo = psig (ze[6 + uh][j]);
                BR[uh * 4 + j] = (short)f2bf(vo * tanh_c(vi * vg));
            }
        }
        const short8 Bx = *(const short8*)&h2X[1][lr][lg * 8];  // h2f(511), LIN
        float part = 0.f;
#pragma unroll
        for (int mm = 0; mm < 4; ++mm) {
            const int row = mm * 16 + lr;
            const short8 A0 = ldfrag_lin(w_fc1 + row * 64 + lg * 8);   // cols 0-31 LIN
            const short8 A1 = ldfrag_s2(w_fc1 + row * 64 + 32, lg);    // cols 32-63 s2
            short8 bf = {0, 0, 0, 0, 0, 0, 0, 0};
            if (lg == 0) bf[0] = (short)f2bf(b_fc1[row]);
            f32x4 a = {0.f, 0.f, 0.f, 0.f};
            a = MFMA16(A0, Bx, a);
            a = MFMA16(A1, BR, a);
            a = MFMA16(bf, Bb, a);
#pragma unroll
            for (int j = 0; j < 4; ++j)
                part += fmaxf(a[j], 0.f) * w_out[mm * 16 + lg * 4 + j];
        }
        part += __shfl_xor(part, 16, 64);
        part += __shfl_xor(part, 32, 64);
        if (l < 16) out[bt * 16 + lr] = psig(NL2E * (part + b_out[0]));
    }
}

// ---------------------------------------------------------------------------
extern "C" void kernel_launch(void* const* d_in, const int* in_sizes, int n_in,
                              void* d_out, int out_size, void* d_ws, size_t ws_size,
                              hipStream_t stream) {
    const float* x     = (const float*)d_in[0];
    const float* wih1f = (const float*)d_in[1];
    const float* whh1f = (const float*)d_in[2];
    const float* b1f   = (const float*)d_in[3];
    const float* wih1r = (const float*)d_in[4];
    const float* whh1r = (const float*)d_in[5];
    const float* b1r   = (const float*)d_in[6];
    const float* wih2f = (const float*)d_in[7];
    const float* whh2f = (const float*)d_in[8];
    const float* b2f   = (const float*)d_in[9];
    const float* wih2r = (const float*)d_in[10];
    // d_in[11] = whh2r unused: layer-2 reverse runs exactly one step from zero state
    const float* b2r   = (const float*)d_in[12];
    const float* w_fc1 = (const float*)d_in[13];
    const float* b_fc1 = (const float*)d_in[14];
    const float* w_out = (const float*)d_in[15];
    const float* b_out = (const float*)d_in[16];
    float* out = (float*)d_out;

    // ws >= 128 MB proven: rounds 8-10 executed the 128 MB dual-archive path.
    unsigned short* arch_f = (unsigned short*)d_ws;
    unsigned short* arch_r = arch_f + (size_t)64 * T_STEPS * 16 * 64;

    l1dual_kernel<<<dim3(128), dim3(256), 0, stream>>>(
        x, whh1f, wih1f, b1f, whh1r, wih1r, b1r, arch_f, arch_r);
    l2top_kernel<<<dim3(64), dim3(512), 0, stream>>>(
        wih2f, whh2f, b2f, wih2r, b2r,
        w_fc1, b_fc1, w_out, b_out, arch_f, arch_r, out);
}

// Round 12
// 790.321 us; speedup vs baseline: 2.4406x; 1.0028x over previous
//
#include <hip/hip_runtime.h>
#include <hip/hip_bf16.h>
#include <math.h>

#define T_STEPS 512
#define BATCH   1024
#define NL2E    (-1.44269504f)   // -log2(e)

typedef __attribute__((ext_vector_type(8))) short short8;
typedef __attribute__((ext_vector_type(4))) float f32x4;

#define MFMA16(A, B, C) __builtin_amdgcn_mfma_f32_16x16x32_bf16((A), (B), (C), 0, 0, 0)

// LDS-only barrier (round-9-verified safe).
__device__ __forceinline__ void lds_barrier() {
    asm volatile("s_waitcnt lgkmcnt(0)" ::: "memory");
    __builtin_amdgcn_s_barrier();
}

// Raw-hardware activations. Inputs are PRESCALED: zs = -log2e*z (sigmoid),
// zs = -2log2e*z (tanh). sigma(z) = rcp(1+2^zs); tanh(z) = 2*rcp(1+2^zs)-1.
// (__fdividef in HIP headers is plain x/y -> IEEE div sequence ~12 instrs;
// that was ~half the per-step VALU issue. rcp+exp2 = 2 instrs.)
__device__ __forceinline__ float psig(float zs) {
    return __builtin_amdgcn_rcpf(1.0f + __builtin_amdgcn_exp2f(zs));
}
__device__ __forceinline__ float ptanh(float zs) {
    return fmaf(2.0f, __builtin_amdgcn_rcpf(1.0f + __builtin_amdgcn_exp2f(zs)), -1.0f);
}
__device__ __forceinline__ float tanh_c(float c) {   // unprescaled input
    return fmaf(2.0f, __builtin_amdgcn_rcpf(
        1.0f + __builtin_amdgcn_exp2f(2.0f * NL2E * c)), -1.0f);
}
__device__ __forceinline__ unsigned short f2bf(float f) {
    unsigned int u = __float_as_uint(f);
    u += 0x7fffu + ((u >> 16) & 1u);
    return (unsigned short)(u >> 16);
}
// linear k-slot gather with scale folded in before bf16 rounding
__device__ __forceinline__ short8 ldfrag_lin_s(const float* __restrict__ p, float s) {
    short8 r;
#pragma unroll
    for (int e = 0; e < 8; ++e) r[e] = (short)f2bf(p[e] * s);
    return r;
}
__device__ __forceinline__ short8 ldfrag_lin(const float* __restrict__ p) {
    return ldfrag_lin_s(p, 1.0f);
}
// sigma2 gather: k-slot (lg,e) <-> col (e>>2)*16 + lg*4 + (e&3)
__device__ __forceinline__ short8 ldfrag_s2(const float* __restrict__ p, int lg) {
    short8 r;
#pragma unroll
    for (int e = 0; e < 8; ++e) r[e] = (short)f2bf(p[(e >> 2) * 16 + lg * 4 + (e & 3)]);
    return r;
}

// ===========================================================================
// K1-dual: layer-1 BOTH directions concurrently. 128 blocks x 256 thr.
// Even blocks: forward -> arch_f; odd: reverse -> arch_r. Weights prescaled
// by -log2e (gates i,f,o) / -2log2e (gate g) at fragment load.
// ===========================================================================
__global__ __launch_bounds__(256, 1) void l1dual_kernel(
    const float* __restrict__ x,
    const float* __restrict__ whh1f, const float* __restrict__ wih1f, const float* __restrict__ b1f,
    const float* __restrict__ whh1r, const float* __restrict__ wih1r, const float* __restrict__ b1r,
    unsigned short* __restrict__ arch_f, unsigned short* __restrict__ arch_r)
{
    __shared__ __align__(16) float xT[T_STEPS][20];
    __shared__ __align__(16) short hT[2][16][72];

    const int blk = blockIdx.x;
    const int dir = blk & 1;            // 0 = fwd, 1 = rev
    const int tile = blk >> 1;
    const int tid = threadIdx.x;
    const int wv = tid >> 6, l = tid & 63, lg = l >> 4, lr = l & 15;

    const float* __restrict__ whh = dir ? whh1r : whh1f;
    const float* __restrict__ wih = dir ? wih1r : wih1f;
    const float* __restrict__ bbp = dir ? b1r : b1f;
    unsigned short* __restrict__ archb =
        (dir ? arch_r : arch_f) + (size_t)tile * T_STEPS * 16 * 64;

    for (int i = tid; i < T_STEPS * 16; i += 256) {
        const int b = i >> 9, t = i & 511;
        xT[t][b] = x[(size_t)(tile * 16 + b) * T_STEPS + t];
    }
    for (int i = tid; i < 2 * 16 * 72; i += 256) ((short*)hT)[i] = 0;

    short8 BW[8]; float wihv[4], bvv[4];
#pragma unroll
    for (int g = 0; g < 4; ++g) {
        const float sf = (g == 2) ? 2.0f * NL2E : NL2E;
        const int row = g * 64 + wv * 16 + lr;
        BW[2 * g]     = ldfrag_lin_s(whh + row * 64 + lg * 8, sf);
        BW[2 * g + 1] = ldfrag_lin_s(whh + row * 64 + 32 + lg * 8, sf);
        wihv[g] = wih[row] * sf; bvv[g] = bbp[row] * sf;
    }
    float cst[4] = {0.f, 0.f, 0.f, 0.f};
    __syncthreads();

    for (int i = 0; i < T_STEPS; ++i) {
        const int t = dir ? (T_STEPS - 1 - i) : i;
        const int rp = (t + 1) & 1;     // parity of previous step (both dirs)
        const short8 a0 = *(const short8*)&hT[rp][lr][lg * 8];
        const short8 a1 = *(const short8*)&hT[rp][lr][32 + lg * 8];
        f32x4 z[4];
#pragma unroll
        for (int g = 0; g < 4; ++g) {
            f32x4 za = {0.f, 0.f, 0.f, 0.f}, zb = {0.f, 0.f, 0.f, 0.f};
            za = MFMA16(a0, BW[2 * g], za);
            zb = MFMA16(a1, BW[2 * g + 1], zb);
            z[g] = za + zb;
        }
        const float4 x4v = *(const float4*)&xT[t][lg * 4];
        const float xa[4] = {x4v.x, x4v.y, x4v.z, x4v.w};
#pragma unroll
        for (int j = 0; j < 4; ++j) {
            const float vi = psig (z[0][j] + fmaf(xa[j], wihv[0], bvv[0]));
            const float vf = psig (z[1][j] + fmaf(xa[j], wihv[1], bvv[1]));
            const float vg = ptanh(z[2][j] + fmaf(xa[j], wihv[2], bvv[2]));
            const float vo = psig (z[3][j] + fmaf(xa[j], wihv[3], bvv[3]));
            cst[j] = fmaf(vf, cst[j], vi * vg);
            const float h = vo * tanh_c(cst[j]);
            const unsigned short hb = f2bf(h);
            hT[t & 1][lg * 4 + j][wv * 16 + lr] = (short)hb;
            archb[((size_t)t * 16 + lg * 4 + j) * 64 + wv * 16 + lr] = hb;
        }
        lds_barrier();
    }
}

// ===========================================================================
// K3: layer-2 forward recurrence + rev step + head. 64 blocks x 512 thr.
// Gate-interleaved rows: orig(r) = (r&3)*32 + 4*wv + (r>>2); lane's 4 C
// values are gates i,f,g,o of unit (4*wv+lg), batch lr. All five A-frags
// prescaled per-row by the row's gate factor (gate = lr&3).
// ===========================================================================
__global__ __launch_bounds__(512, 1) void l2top_kernel(
    const float* __restrict__ wih2f, const float* __restrict__ whh2f, const float* __restrict__ b2f,
    const float* __restrict__ wih2r, const float* __restrict__ b2r,
    const float* __restrict__ w_fc1, const float* __restrict__ b_fc1,
    const float* __restrict__ w_out, const float* __restrict__ b_out,
    const unsigned short* __restrict__ arch_f, const unsigned short* __restrict__ arch_r,
    float* __restrict__ out)
{
    __shared__ __align__(16) short h2X[2][16][40];

    const int bt = blockIdx.x, tid = threadIdx.x;
    const int wv = tid >> 6, l = tid & 63, lg = l >> 4, lr = l & 15;
    const unsigned short* __restrict__ af = arch_f + (size_t)bt * T_STEPS * 16 * 64;
    const unsigned short* __restrict__ ar = arch_r + (size_t)bt * T_STEPS * 16 * 64;

    const int orow = (lr & 3) * 32 + 4 * wv + (lr >> 2);   // interleaved row map
    const float sfr = ((lr & 3) == 2) ? 2.0f * NL2E : NL2E;  // this A-row's gate factor
    short8 AF[5];
    AF[0] = ldfrag_lin_s(wih2f + orow * 128 + lg * 8, sfr);        // hf k 0-31
    AF[1] = ldfrag_lin_s(wih2f + orow * 128 + 32 + lg * 8, sfr);   // hf k 32-63
    AF[2] = ldfrag_lin_s(wih2f + orow * 128 + 64 + lg * 8, sfr);   // hr k 0-31
    AF[3] = ldfrag_lin_s(wih2f + orow * 128 + 96 + lg * 8, sfr);   // hr k 32-63
    AF[4] = ldfrag_lin_s(whh2f + orow * 32 + lg * 8, sfr);         // h2 k 0-31
    float b2v[4];
#pragma unroll
    for (int j = 0; j < 4; ++j)
        b2v[j] = b2f[j * 32 + 4 * wv + lg] * ((j == 2) ? 2.0f * NL2E : NL2E);

    for (int i = tid; i < 2 * 16 * 40; i += 512) ((short*)h2X)[i] = 0;

    // prologue: zcur = zpre(0); prefetch frags for step 1
    short8 pf0 = *(const short8*)(af + (size_t)lr * 64 + lg * 8);
    short8 pf1 = *(const short8*)(af + (size_t)lr * 64 + 32 + lg * 8);
    short8 pr0 = *(const short8*)(ar + (size_t)lr * 64 + lg * 8);
    short8 pr1 = *(const short8*)(ar + (size_t)lr * 64 + 32 + lg * 8);
    f32x4 zcur = {0.f, 0.f, 0.f, 0.f};
    zcur = MFMA16(AF[0], pf0, zcur);
    zcur = MFMA16(AF[1], pf1, zcur);
    zcur = MFMA16(AF[2], pr0, zcur);
    zcur = MFMA16(AF[3], pr1, zcur);
    pf0 = *(const short8*)(af + (size_t)(1 * 16 + lr) * 64 + lg * 8);
    pf1 = *(const short8*)(af + (size_t)(1 * 16 + lr) * 64 + 32 + lg * 8);
    pr0 = *(const short8*)(ar + (size_t)(1 * 16 + lr) * 64 + lg * 8);
    pr1 = *(const short8*)(ar + (size_t)(1 * 16 + lr) * 64 + 32 + lg * 8);

    float c2 = 0.f;
    __syncthreads();

    for (int s = 0; s < T_STEPS; ++s) {
        // ---- critical path: Whh2.h2(s-1) + zcur -> gates -> c2 -> h2(s)
        const short8 bh = *(const short8*)&h2X[(s + 1) & 1][lr][lg * 8];
        const f32x4 z = MFMA16(AF[4], bh, zcur);
        // ---- off-path: zpre(s+1) from prefetched frags; prefetch (s+2)
        f32x4 znxt = {0.f, 0.f, 0.f, 0.f};
        znxt = MFMA16(AF[0], pf0, znxt);
        znxt = MFMA16(AF[1], pf1, znxt);
        znxt = MFMA16(AF[2], pr0, znxt);
        znxt = MFMA16(AF[3], pr1, znxt);
        if (s + 2 < T_STEPS) {
            pf0 = *(const short8*)(af + (size_t)((s + 2) * 16 + lr) * 64 + lg * 8);
            pf1 = *(const short8*)(af + (size_t)((s + 2) * 16 + lr) * 64 + 32 + lg * 8);
            pr0 = *(const short8*)(ar + (size_t)((s + 2) * 16 + lr) * 64 + lg * 8);
            pr1 = *(const short8*)(ar + (size_t)((s + 2) * 16 + lr) * 64 + 32 + lg * 8);
        }
        // ---- lane-local gates (j: 0=i 1=f 2=g 3=o of unit 4*wv+lg, batch lr)
        const float vi = psig (z[0] + b2v[0]);
        const float vf = psig (z[1] + b2v[1]);
        const float vg = ptanh(z[2] + b2v[2]);
        const float vo = psig (z[3] + b2v[3]);
        c2 = fmaf(vf, c2, vi * vg);
        h2X[s & 1][lr][4 * wv + lg] = (short)f2bf(vo * tanh_c(c2));
        zcur = znxt;
        lds_barrier();
    }

    // ===== epilogue (wave 0): L2-reverse single step @ T-1 + MLP head ======
    if (wv == 0) {
        short8 Bb = {0, 0, 0, 0, 0, 0, 0, 0};
        if (lg == 0) Bb[0] = (short)0x3F80;                   // B = [1, 0, ...]
        const short8 f0 = *(const short8*)(af + (size_t)((T_STEPS - 1) * 16 + lr) * 64 + lg * 8);
        const short8 f1 = *(const short8*)(af + (size_t)((T_STEPS - 1) * 16 + lr) * 64 + 32 + lg * 8);
        const short8 r0 = *(const short8*)(ar + (size_t)((T_STEPS - 1) * 16 + lr) * 64 + lg * 8);
        const short8 r1 = *(const short8*)(ar + (size_t)((T_STEPS - 1) * 16 + lr) * 64 + 32 + lg * 8);
        f32x4 ze[8];
#pragma unroll
        for (int mm = 0; mm < 8; ++mm) {
            const int row = mm * 16 + lr;                     // gate-major LIN rows
            const float sfe = ((mm >> 1) == 2) ? 2.0f * NL2E : NL2E;
            const short8 A0 = ldfrag_lin_s(wih2r + row * 128 + lg * 8, sfe);
            const short8 A1 = ldfrag_lin_s(wih2r + row * 128 + 32 + lg * 8, sfe);
            const short8 A2 = ldfrag_lin_s(wih2r + row * 128 + 64 + lg * 8, sfe);
            const short8 A3 = ldfrag_lin_s(wih2r + row * 128 + 96 + lg * 8, sfe);
            short8 bf = {0, 0, 0, 0, 0, 0, 0, 0};
            if (lg == 0) bf[0] = (short)f2bf(b2r[row] * sfe);
            f32x4 za = {0.f, 0.f, 0.f, 0.f}, zb = {0.f, 0.f, 0.f, 0.f};
            za = MFMA16(A0, f0, za);
            za = MFMA16(A2, r0, za);
            za = MFMA16(bf, Bb, za);
            zb = MFMA16(A1, f1, zb);
            zb = MFMA16(A3, r1, zb);
            ze[mm] = za + zb;
        }
        short8 BR = {0, 0, 0, 0, 0, 0, 0, 0};   // h2r(511), lane-natural sigma2
#pragma unroll
        for (int uh = 0; uh < 2; ++uh) {
#pragma unroll
            for (int j = 0; j < 4; ++j) {
                const float vi = psig (ze[uh][j]);            // c0=0: f-gate irrelevant
                const float vg = ptanh(ze[4 + uh][j]);
                const float vo = psig (ze[6 + uh][j]);
                BR[uh * 4 + j] = (short)f2bf(vo * tanh_c(vi * vg));
            }
        }
        const short8 Bx = *(const short8*)&h2X[1][lr][lg * 8];  // h2f(511), LIN
        float part = 0.f;
#pragma unroll
        for (int mm = 0; mm < 4; ++mm) {
            const int row = mm * 16 + lr;
            const short8 A0 = ldfrag_lin(w_fc1 + row * 64 + lg * 8);   // cols 0-31 LIN
            const short8 A1 = ldfrag_s2(w_fc1 + row * 64 + 32, lg);    // cols 32-63 s2
            short8 bf = {0, 0, 0, 0, 0, 0, 0, 0};
            if (lg == 0) bf[0] = (short)f2bf(b_fc1[row]);
            f32x4 a = {0.f, 0.f, 0.f, 0.f};
            a = MFMA16(A0, Bx, a);
            a = MFMA16(A1, BR, a);
            a = MFMA16(bf, Bb, a);
#pragma unroll
            for (int j = 0; j < 4; ++j)
                part += fmaxf(a[j], 0.f) * w_out[mm * 16 + lg * 4 + j];
        }
        part += __shfl_xor(part, 16, 64);
        part += __shfl_xor(part, 32, 64);
        if (l < 16) out[bt * 16 + lr] = psig(NL2E * (part + b_out[0]));
    }
}

// ---------------------------------------------------------------------------
extern "C" void kernel_launch(void* const* d_in, const int* in_sizes, int n_in,
                              void* d_out, int out_size, void* d_ws, size_t ws_size,
                              hipStream_t stream) {
    const float* x     = (const float*)d_in[0];
    const float* wih1f = (const float*)d_in[1];
    const float* whh1f = (const float*)d_in[2];
    const float* b1f   = (const float*)d_in[3];
    const float* wih1r = (const float*)d_in[4];
    const float* whh1r = (const float*)d_in[5];
    const float* b1r   = (const float*)d_in[6];
    const float* wih2f = (const float*)d_in[7];
    const float* whh2f = (const float*)d_in[8];
    const float* b2f   = (const float*)d_in[9];
    const float* wih2r = (const float*)d_in[10];
    // d_in[11] = whh2r unused: layer-2 reverse runs exactly one step from zero state
    const float* b2r   = (const float*)d_in[12];
    const float* w_fc1 = (const float*)d_in[13];
    const float* b_fc1 = (const float*)d_in[14];
    const float* w_out = (const float*)d_in[15];
    const float* b_out = (const float*)d_in[16];
    float* out = (float*)d_out;

    // ws >= 128 MB proven: rounds 8-10 executed the 128 MB dual-archive path.
    unsigned short* arch_f = (unsigned short*)d_ws;
    unsigned short* arch_r = arch_f + (size_t)64 * T_STEPS * 16 * 64;

    l1dual_kernel<<<dim3(128), dim3(256), 0, stream>>>(
        x, whh1f, wih1f, b1f, whh1r, wih1r, b1r, arch_f, arch_r);
    l2top_kernel<<<dim3(64), dim3(512), 0, stream>>>(
        wih2f, whh2f, b2f, wih2r, b2r,
        w_fc1, b_fc1, w_out, b_out, arch_f, arch_r, out);
}